// Round 2
// baseline (1981.647 us; speedup 1.0000x reference)
//
#include <hip/hip_runtime.h>
#include <math.h>

#define NN 100000
#define NE 800000
#define NH 128
#define NC 40

// ---------------- CSR build ----------------
__global__ void hist_kernel(const int* __restrict__ dst, int* __restrict__ cnt, int E) {
  int i = blockIdx.x * 256 + threadIdx.x;
  if (i < E) atomicAdd(&cnt[dst[i]], 1);
}

__global__ __launch_bounds__(1024) void scan_kernel(const int* __restrict__ cnt,
                                                    int* __restrict__ rp, int n) {
  __shared__ int buf[1024];
  __shared__ int carry_s;
  int tid = threadIdx.x;
  if (tid == 0) carry_s = 0;
  __syncthreads();
  for (int base = 0; base < n; base += 1024) {
    int i = base + tid;
    int v = (i < n) ? cnt[i] : 0;
    buf[tid] = v;
    __syncthreads();
    for (int off = 1; off < 1024; off <<= 1) {
      int t = (tid >= off) ? buf[tid - off] : 0;
      __syncthreads();
      buf[tid] += t;
      __syncthreads();
    }
    int incl = buf[tid];
    if (i < n) rp[i] = carry_s + incl - v;  // exclusive scan
    __syncthreads();
    if (tid == 1023) carry_s += incl;       // incl of last thread == chunk total
    __syncthreads();
  }
  if (tid == 0) rp[n] = carry_s;
}

__global__ void copy_kernel(const int* __restrict__ a, int* __restrict__ b, int n) {
  int i = blockIdx.x * 256 + threadIdx.x;
  if (i < n) b[i] = a[i];
}

__global__ void scatter_kernel(const int* __restrict__ src, const int* __restrict__ dst,
                               const float* __restrict__ ew, int* __restrict__ off,
                               int* __restrict__ cs, float* __restrict__ cw, int E) {
  int i = blockIdx.x * 256 + threadIdx.x;
  if (i < E) {
    int p = atomicAdd(&off[dst[i]], 1);
    cs[p] = src[i];
    cw[p] = ew[i];
  }
}

// fused multiply-add of a scalar into a float4 accumulator (macro-hygiene-safe)
__device__ __forceinline__ void fma4(float4& a, float s, const float4& w) {
  a.x = fmaf(s, w.x, a.x);
  a.y = fmaf(s, w.y, a.y);
  a.z = fmaf(s, w.z, a.z);
  a.w = fmaf(s, w.w, a.w);
}

// ---------------- dense matmul: [NN,128] @ [128,128] ----------------
// 32 rows/block, 256 threads: cg=tid&31 -> 4 cols, rg=tid>>5 -> 4 rows (stride 8)
__global__ __launch_bounds__(256) void matmul128_kernel(const float* __restrict__ H,
                                                        const float* __restrict__ W,
                                                        float* __restrict__ S) {
  __shared__ float4 Ws4[128 * 32];  // W[k][c] row-major, 64 KB
  __shared__ float4 Hs4[32 * 32];   // 32 rows x 128, 16 KB
  int tid = threadIdx.x;
  size_t row0 = (size_t)blockIdx.x * 32;

  const float4* W4 = (const float4*)W;
  for (int i = tid; i < 4096; i += 256) Ws4[i] = W4[i];
  const float4* H4 = (const float4*)(H + row0 * NH);
  for (int i = tid; i < 1024; i += 256) Hs4[i] = H4[i];
  __syncthreads();

  int cg = tid & 31;   // cols 4*cg .. 4*cg+3
  int rg = tid >> 5;   // rows rg, rg+8, rg+16, rg+24
  float4 acc0 = {0,0,0,0}, acc1 = {0,0,0,0}, acc2 = {0,0,0,0}, acc3 = {0,0,0,0};

  for (int kk = 0; kk < 32; ++kk) {
    float4 h0 = Hs4[(rg     ) * 32 + kk];
    float4 h1 = Hs4[(rg +  8) * 32 + kk];
    float4 h2 = Hs4[(rg + 16) * 32 + kk];
    float4 h3 = Hs4[(rg + 24) * 32 + kk];
    float4 w0 = Ws4[(4 * kk + 0) * 32 + cg];
    float4 w1 = Ws4[(4 * kk + 1) * 32 + cg];
    float4 w2 = Ws4[(4 * kk + 2) * 32 + cg];
    float4 w3 = Ws4[(4 * kk + 3) * 32 + cg];
    fma4(acc0, h0.x, w0); fma4(acc0, h0.y, w1); fma4(acc0, h0.z, w2); fma4(acc0, h0.w, w3);
    fma4(acc1, h1.x, w0); fma4(acc1, h1.y, w1); fma4(acc1, h1.z, w2); fma4(acc1, h1.w, w3);
    fma4(acc2, h2.x, w0); fma4(acc2, h2.y, w1); fma4(acc2, h2.z, w2); fma4(acc2, h2.w, w3);
    fma4(acc3, h3.x, w0); fma4(acc3, h3.y, w1); fma4(acc3, h3.z, w2); fma4(acc3, h3.w, w3);
  }
  float4* S4 = (float4*)(S + row0 * NH);
  S4[(rg     ) * 32 + cg] = acc0;
  S4[(rg +  8) * 32 + cg] = acc1;
  S4[(rg + 16) * 32 + cg] = acc2;
  S4[(rg + 24) * 32 + cg] = acc3;
}

// ---------------- dense matmul: [NN,128] @ [128,40] ----------------
__global__ __launch_bounds__(256) void matmul40_kernel(const float* __restrict__ H,
                                                       const float* __restrict__ W,
                                                       float* __restrict__ S) {
  __shared__ float Ws[128 * NC + 64];  // padded (lanes c>=40 read junk, discarded)
  __shared__ float4 Hs4[32 * 32];
  int tid = threadIdx.x;
  size_t row0 = (size_t)blockIdx.x * 32;

  for (int i = tid; i < 128 * NC / 4; i += 256) ((float4*)Ws)[i] = ((const float4*)W)[i];
  const float4* H4 = (const float4*)(H + row0 * NH);
  for (int i = tid; i < 1024; i += 256) Hs4[i] = H4[i];
  __syncthreads();

  int c = tid & 63;    // col (active if < 40)
  int rg = tid >> 6;   // rows rg + 4*r, r=0..7
  float acc[8];
#pragma unroll
  for (int r = 0; r < 8; ++r) acc[r] = 0.f;

  for (int kk = 0; kk < 32; ++kk) {
    float4 hv[8];
#pragma unroll
    for (int r = 0; r < 8; ++r) hv[r] = Hs4[(rg + 4 * r) * 32 + kk];
#pragma unroll
    for (int j = 0; j < 4; ++j) {
      float wv = Ws[(4 * kk + j) * NC + c];
#pragma unroll
      for (int r = 0; r < 8; ++r) {
        float s = (j == 0) ? hv[r].x : (j == 1) ? hv[r].y : (j == 2) ? hv[r].z : hv[r].w;
        acc[r] = fmaf(s, wv, acc[r]);
      }
    }
  }
  if (c < NC) {
#pragma unroll
    for (int r = 0; r < 8; ++r) S[(row0 + rg + 4 * r) * NC + c] = acc[r];
  }
}

// ---------------- spmm (128-wide) + bias + relu (+ residual), in-place safe ----------------
__global__ __launch_bounds__(128) void spmm128_kernel(const float* __restrict__ S,
                                                      const int* __restrict__ rp,
                                                      const int* __restrict__ cs,
                                                      const float* __restrict__ cw,
                                                      const float* __restrict__ b,
                                                      const float* __restrict__ Hin,
                                                      float* __restrict__ Hout,
                                                      int residual) {
  int node = blockIdx.x;
  int tid = threadIdx.x;
  int e0 = rp[node], e1 = rp[node + 1];
  float acc = 0.f;
  for (int e = e0; e < e1; ++e) {
    int s = cs[e];
    float w = cw[e];
    acc = fmaf(w, S[(size_t)s * NH + tid], acc);
  }
  float v = fmaxf(acc + b[tid], 0.f);
  if (residual) v += Hin[(size_t)node * NH + tid];
  Hout[(size_t)node * NH + tid] = v;
}

// ---------------- final spmm (40-wide) + bias + relu + log_softmax ----------------
__global__ __launch_bounds__(64) void spmm40_lsm_kernel(const float* __restrict__ S,
                                                        const int* __restrict__ rp,
                                                        const int* __restrict__ cs,
                                                        const float* __restrict__ cw,
                                                        const float* __restrict__ b,
                                                        float* __restrict__ out) {
  int node = blockIdx.x;
  int tid = threadIdx.x;
  int e0 = rp[node], e1 = rp[node + 1];
  float acc = 0.f;
  if (tid < NC) {
    for (int e = e0; e < e1; ++e)
      acc = fmaf(cw[e], S[(size_t)cs[e] * NC + tid], acc);
    acc = fmaxf(acc + b[tid], 0.f);
  }
  float v = (tid < NC) ? acc : -INFINITY;
  float m = v;
#pragma unroll
  for (int off = 32; off; off >>= 1) m = fmaxf(m, __shfl_xor(m, off));
  float ex = (tid < NC) ? expf(v - m) : 0.f;
  float ssum = ex;
#pragma unroll
  for (int off = 32; off; off >>= 1) ssum += __shfl_xor(ssum, off);
  if (tid < NC) out[(size_t)node * NC + tid] = v - m - logf(ssum);
}

extern "C" void kernel_launch(void* const* d_in, const int* in_sizes, int n_in,
                              void* d_out, int out_size, void* d_ws, size_t ws_size,
                              hipStream_t stream) {
  const float* x   = (const float*)d_in[0];
  const int*   src = (const int*)d_in[1];
  const int*   dst = (const int*)d_in[2];
  const float* ew  = (const float*)d_in[3];
  const float* W1  = (const float*)d_in[4];
  const float* Wh  = (const float*)d_in[5];
  const float* W10 = (const float*)d_in[6];
  const float* b1  = (const float*)d_in[7];
  const float* bh  = (const float*)d_in[8];
  const float* b10 = (const float*)d_in[9];
  float* out = (float*)d_out;

  // workspace layout (256B aligned)
  char* p = (char*)d_ws;
  int*   rp   = (int*)p;   p += (((size_t)(NN + 1) * 4 + 255) / 256) * 256;
  int*   roff = (int*)p;   p += (((size_t)NN * 4 + 255) / 256) * 256;
  int*   cs   = (int*)p;   p += (size_t)NE * 4;
  float* cw   = (float*)p; p += (size_t)NE * 4;
  float* h    = (float*)p; p += (size_t)NN * NH * 4;
  float* sup  = (float*)p; p += (size_t)NN * NH * 4;

  // ---- build CSR (per launch; ws is re-poisoned every call) ----
  hipMemsetAsync(roff, 0, (size_t)NN * 4, stream);
  hist_kernel<<<(NE + 255) / 256, 256, 0, stream>>>(dst, roff, NE);
  scan_kernel<<<1, 1024, 0, stream>>>(roff, rp, NN);
  copy_kernel<<<(NN + 255) / 256, 256, 0, stream>>>(rp, roff, NN);
  scatter_kernel<<<(NE + 255) / 256, 256, 0, stream>>>(src, dst, ew, roff, cs, cw, NE);

  // ---- layer 1 ----
  matmul128_kernel<<<NN / 32, 256, 0, stream>>>(x, W1, sup);
  spmm128_kernel<<<NN, 128, 0, stream>>>(sup, rp, cs, cw, b1, h, h, 0);

  // ---- 8 hidden residual layers ----
  for (int i = 0; i < 8; ++i) {
    matmul128_kernel<<<NN / 32, 256, 0, stream>>>(h, Wh + (size_t)i * NH * NH, sup);
    spmm128_kernel<<<NN, 128, 0, stream>>>(sup, rp, cs, cw, bh + (size_t)i * NH, h, h, 1);
  }

  // ---- final layer + log_softmax ----
  matmul40_kernel<<<NN / 32, 256, 0, stream>>>(h, W10, sup);
  spmm40_lsm_kernel<<<NN, 64, 0, stream>>>(sup, rp, cs, cw, b10, out);
}

// Round 3
// 1416.594 us; speedup vs baseline: 1.3989x; 1.3989x over previous
//
#include <hip/hip_runtime.h>
#include <math.h>

#define NN 100000
#define NE 800000
#define NH 128
#define NC 40
#define NB_SCAN 98   // ceil(NN/1024)

typedef __attribute__((ext_vector_type(8))) short short8;
typedef __attribute__((ext_vector_type(4))) float floatx4;

__device__ __forceinline__ unsigned short f2b(float f) {
  union { float f; unsigned int u; } x; x.f = f;
  unsigned int r = x.u + 0x7fff + ((x.u >> 16) & 1);  // RTNE
  return (unsigned short)(r >> 16);
}
__device__ __forceinline__ float b2f(unsigned short h) {
  union { unsigned int u; float f; } x; x.u = ((unsigned int)h) << 16;
  return x.f;
}

// ---------------- CSR build ----------------
__global__ void hist_kernel(const int* __restrict__ dst, int* __restrict__ cnt, int E) {
  int i = blockIdx.x * 256 + threadIdx.x;
  if (i < E) atomicAdd(&cnt[dst[i]], 1);
}

// per-block exclusive scan; writes partial into rp, block totals into bsum
__global__ __launch_bounds__(1024) void scan1_kernel(const int* __restrict__ cnt,
                                                     int* __restrict__ rp,
                                                     int* __restrict__ bsum, int n) {
  __shared__ int buf[1024];
  int t = threadIdx.x, i = blockIdx.x * 1024 + t;
  int v = (i < n) ? cnt[i] : 0;
  buf[t] = v;
  __syncthreads();
  for (int off = 1; off < 1024; off <<= 1) {
    int x = (t >= off) ? buf[t - off] : 0;
    __syncthreads();
    buf[t] += x;
    __syncthreads();
  }
  if (i < n) rp[i] = buf[t] - v;
  if (t == 1023) bsum[blockIdx.x] = buf[t];
}

// scan the (<=128) block sums
__global__ __launch_bounds__(128) void scan2_kernel(const int* __restrict__ bsum,
                                                    int* __restrict__ boff, int nb) {
  __shared__ int buf[128];
  int t = threadIdx.x;
  int v = (t < nb) ? bsum[t] : 0;
  buf[t] = v;
  __syncthreads();
  for (int off = 1; off < 128; off <<= 1) {
    int x = (t >= off) ? buf[t - off] : 0;
    __syncthreads();
    buf[t] += x;
    __syncthreads();
  }
  if (t < nb) boff[t] = buf[t] - v;
  if (t == 127) boff[nb] = buf[t];  // grand total
}

// add block offsets in-place; write rp[n]
__global__ void scan3_kernel(int* __restrict__ rp, const int* __restrict__ boff,
                             int n, int nb) {
  int i = blockIdx.x * 256 + threadIdx.x;
  if (i < n) rp[i] += boff[i >> 10];
  if (i == 0) rp[n] = boff[nb];
}

__global__ void copy_kernel(const int* __restrict__ a, int* __restrict__ b, int n) {
  int i = blockIdx.x * 256 + threadIdx.x;
  if (i < n) b[i] = a[i];
}

__global__ void scatter_kernel(const int* __restrict__ src, const int* __restrict__ dst,
                               const float* __restrict__ ew, int* __restrict__ off,
                               int* __restrict__ cs, float* __restrict__ cw, int E) {
  int i = blockIdx.x * 256 + threadIdx.x;
  if (i < E) {
    int p = atomicAdd(&off[dst[i]], 1);
    cs[p] = src[i];
    cw[p] = ew[i];
  }
}

// ---------------- prep: fp32 -> bf16 converts ----------------
__global__ void xconv_kernel(const float* __restrict__ in, unsigned short* __restrict__ out,
                             int n4) {
  int i = blockIdx.x * 256 + threadIdx.x;
  if (i < n4) {
    float4 v = ((const float4*)in)[i];
    out[4 * i + 0] = f2b(v.x);
    out[4 * i + 1] = f2b(v.y);
    out[4 * i + 2] = f2b(v.z);
    out[4 * i + 3] = f2b(v.w);
  }
}

// 9 dense-128 weights -> bf16, TRANSPOSED: WT[l][n][k] = W_l[k][n]
__global__ void wconv_kernel(const float* __restrict__ W1, const float* __restrict__ Wh,
                             unsigned short* __restrict__ WT) {
  int idx = blockIdx.x * 256 + threadIdx.x;  // 9*16384
  if (idx >= 9 * 16384) return;
  int l = idx >> 14, r = idx & 16383;        // r = k*128+n (coalesced read)
  int k = r >> 7, n = r & 127;
  const float* W = (l == 0) ? W1 : (Wh + (size_t)(l - 1) * 16384);
  WT[(size_t)l * 16384 + n * 128 + k] = f2b(W[r]);
}

// ---------------- MFMA matmul: [NN,128](bf16) @ WT[128,128](bf16) -> Sb bf16 ----------------
// block = 256 thr (4 waves), 64 rows/block; wave w: rows w*16..w*16+15
#define LDH 136  // padded LDS row stride (shorts): 272 B -> 2-way bank alias only
__global__ __launch_bounds__(256) void matmul_mfma_kernel(const unsigned short* __restrict__ Hb,
                                                          const unsigned short* __restrict__ WT,
                                                          unsigned short* __restrict__ Sb) {
  __shared__ unsigned short Ws[128 * LDH];  // W^T[n][k]
  __shared__ unsigned short Hs[64 * LDH];
  int tid = threadIdx.x;
  int row0 = blockIdx.x * 64;

  for (int c = tid; c < 2048; c += 256) {   // 128 rows x 16 chunks of 8 shorts
    int r = c >> 4, s = c & 15;
    *(short8*)(Ws + r * LDH + s * 8) = *(const short8*)(WT + r * 128 + s * 8);
  }
  for (int c = tid; c < 1024; c += 256) {   // 64 rows x 16 chunks
    int r = c >> 4, s = c & 15;
    int gr = row0 + r; if (gr >= NN) gr = NN - 1;
    *(short8*)(Hs + r * LDH + s * 8) = *(const short8*)(Hb + (size_t)gr * 128 + s * 8);
  }
  __syncthreads();

  int wave = tid >> 6;
  int lane = tid & 63;
  int m = lane & 15;
  int quad = lane >> 4;

  floatx4 acc[8];
#pragma unroll
  for (int nt = 0; nt < 8; ++nt) acc[nt] = (floatx4){0.f, 0.f, 0.f, 0.f};

  const unsigned short* arow = Hs + (wave * 16 + m) * LDH + quad * 8;
#pragma unroll
  for (int ks = 0; ks < 4; ++ks) {
    short8 a = *(const short8*)(arow + ks * 32);
#pragma unroll
    for (int nt = 0; nt < 8; ++nt) {
      short8 b = *(const short8*)(Ws + (nt * 16 + m) * LDH + quad * 8 + ks * 32);
      acc[nt] = __builtin_amdgcn_mfma_f32_16x16x32_bf16(a, b, acc[nt], 0, 0, 0);
    }
  }
  // D: row = quad*4+reg (in wave's 16-row tile), col = nt*16 + m
#pragma unroll
  for (int nt = 0; nt < 8; ++nt) {
#pragma unroll
    for (int reg = 0; reg < 4; ++reg) {
      int gr = row0 + wave * 16 + quad * 4 + reg;
      if (gr < NN) Sb[(size_t)gr * 128 + nt * 16 + m] = f2b(acc[nt][reg]);
    }
  }
}

// ---------------- spmm (bf16 gather) + bias + relu (+ residual) ----------------
__global__ __launch_bounds__(128) void spmm128b_kernel(const unsigned short* __restrict__ Sb,
                                                       const int* __restrict__ rp,
                                                       const int* __restrict__ cs,
                                                       const float* __restrict__ cw,
                                                       const float* __restrict__ b,
                                                       const float* __restrict__ Hin,
                                                       float* __restrict__ Hout,
                                                       unsigned short* __restrict__ HbOut,
                                                       int residual) {
  int node = blockIdx.x;
  int tid = threadIdx.x;
  int e0 = rp[node], e1 = rp[node + 1];
  float acc = 0.f;
  for (int e = e0; e < e1; ++e)
    acc = fmaf(cw[e], b2f(Sb[(size_t)cs[e] * NH + tid]), acc);
  float v = fmaxf(acc + b[tid], 0.f);
  if (residual) v += Hin[(size_t)node * NH + tid];
  Hout[(size_t)node * NH + tid] = v;
  HbOut[(size_t)node * NH + tid] = f2b(v);
}

// ---------------- dense matmul: [NN,128](f32) @ [128,40] ----------------
__global__ __launch_bounds__(256) void matmul40_kernel(const float* __restrict__ H,
                                                       const float* __restrict__ W,
                                                       float* __restrict__ S) {
  __shared__ float Wsf[128 * NC + 64];
  __shared__ float4 Hs4[32 * 32];
  int tid = threadIdx.x;
  size_t row0 = (size_t)blockIdx.x * 32;

  for (int i = tid; i < 128 * NC / 4; i += 256) ((float4*)Wsf)[i] = ((const float4*)W)[i];
  const float4* H4 = (const float4*)(H + row0 * NH);
  for (int i = tid; i < 1024; i += 256) Hs4[i] = H4[i];
  __syncthreads();

  int c = tid & 63;
  int rg = tid >> 6;
  float acc[8];
#pragma unroll
  for (int r = 0; r < 8; ++r) acc[r] = 0.f;

  for (int kk = 0; kk < 32; ++kk) {
    float4 hv[8];
#pragma unroll
    for (int r = 0; r < 8; ++r) hv[r] = Hs4[(rg + 4 * r) * 32 + kk];
#pragma unroll
    for (int j = 0; j < 4; ++j) {
      float wv = Wsf[(4 * kk + j) * NC + c];
#pragma unroll
      for (int r = 0; r < 8; ++r) {
        float s = (j == 0) ? hv[r].x : (j == 1) ? hv[r].y : (j == 2) ? hv[r].z : hv[r].w;
        acc[r] = fmaf(s, wv, acc[r]);
      }
    }
  }
  if (c < NC) {
#pragma unroll
    for (int r = 0; r < 8; ++r) S[(row0 + rg + 4 * r) * NC + c] = acc[r];
  }
}

// ---------------- final spmm (40-wide) + bias + relu + log_softmax ----------------
__global__ __launch_bounds__(64) void spmm40_lsm_kernel(const float* __restrict__ S,
                                                        const int* __restrict__ rp,
                                                        const int* __restrict__ cs,
                                                        const float* __restrict__ cw,
                                                        const float* __restrict__ b,
                                                        float* __restrict__ out) {
  int node = blockIdx.x;
  int tid = threadIdx.x;
  int e0 = rp[node], e1 = rp[node + 1];
  float acc = 0.f;
  if (tid < NC) {
    for (int e = e0; e < e1; ++e)
      acc = fmaf(cw[e], S[(size_t)cs[e] * NC + tid], acc);
    acc = fmaxf(acc + b[tid], 0.f);
  }
  float v = (tid < NC) ? acc : -INFINITY;
  float m = v;
#pragma unroll
  for (int off = 32; off; off >>= 1) m = fmaxf(m, __shfl_xor(m, off));
  float ex = (tid < NC) ? expf(v - m) : 0.f;
  float ssum = ex;
#pragma unroll
  for (int off = 32; off; off >>= 1) ssum += __shfl_xor(ssum, off);
  if (tid < NC) out[(size_t)node * NC + tid] = v - m - logf(ssum);
}

extern "C" void kernel_launch(void* const* d_in, const int* in_sizes, int n_in,
                              void* d_out, int out_size, void* d_ws, size_t ws_size,
                              hipStream_t stream) {
  const float* x   = (const float*)d_in[0];
  const int*   src = (const int*)d_in[1];
  const int*   dst = (const int*)d_in[2];
  const float* ew  = (const float*)d_in[3];
  const float* W1  = (const float*)d_in[4];
  const float* Wh  = (const float*)d_in[5];
  const float* W10 = (const float*)d_in[6];
  const float* b1  = (const float*)d_in[7];
  const float* bh  = (const float*)d_in[8];
  const float* b10 = (const float*)d_in[9];
  float* out = (float*)d_out;

  // workspace layout (256B-aligned chunks), ~126 MB total
  char* p = (char*)d_ws;
  int*   rp    = (int*)p;            p += (((size_t)(NN + 1) * 4 + 255) / 256) * 256;
  int*   roff  = (int*)p;            p += (((size_t)NN * 4 + 255) / 256) * 256;
  int*   bsum  = (int*)p;            p += 256 * 4;
  int*   boff  = (int*)p;            p += 256 * 4;
  int*   cs    = (int*)p;            p += (size_t)NE * 4;
  float* cw    = (float*)p;          p += (size_t)NE * 4;
  float* h     = (float*)p;          p += (size_t)NN * NH * 4;
  unsigned short* hb   = (unsigned short*)p; p += (size_t)NN * NH * 2;  // also x-bf16
  unsigned short* supb = (unsigned short*)p; p += (size_t)NN * NH * 2;
  float* sup40 = (float*)p;          p += (size_t)NN * NC * 4;
  unsigned short* WT   = (unsigned short*)p; p += (size_t)9 * NH * NH * 2;

  // ---- build CSR ----
  hipMemsetAsync(roff, 0, (size_t)NN * 4, stream);
  hist_kernel<<<(NE + 255) / 256, 256, 0, stream>>>(dst, roff, NE);
  scan1_kernel<<<NB_SCAN, 1024, 0, stream>>>(roff, rp, bsum, NN);
  scan2_kernel<<<1, 128, 0, stream>>>(bsum, boff, NB_SCAN);
  scan3_kernel<<<(NN + 255) / 256, 256, 0, stream>>>(rp, boff, NN, NB_SCAN);
  copy_kernel<<<(NN + 255) / 256, 256, 0, stream>>>(rp, roff, NN);
  scatter_kernel<<<(NE + 255) / 256, 256, 0, stream>>>(src, dst, ew, roff, cs, cw, NE);

  // ---- prep converts ----
  xconv_kernel<<<(NN * NH / 4 + 255) / 256, 256, 0, stream>>>(x, hb, NN * NH / 4);
  wconv_kernel<<<(9 * 16384 + 255) / 256, 256, 0, stream>>>(W1, Wh, WT);

  // ---- layer 1 ----
  matmul_mfma_kernel<<<(NN + 63) / 64, 256, 0, stream>>>(hb, WT, supb);
  spmm128b_kernel<<<NN, 128, 0, stream>>>(supb, rp, cs, cw, b1, h, h, hb, 0);

  // ---- 8 hidden residual layers ----
  for (int i = 0; i < 8; ++i) {
    matmul_mfma_kernel<<<(NN + 63) / 64, 256, 0, stream>>>(hb, WT + (size_t)(i + 1) * NH * NH, supb);
    spmm128b_kernel<<<NN, 128, 0, stream>>>(supb, rp, cs, cw, bh + (size_t)i * NH, h, h, hb, 1);
  }

  // ---- final layer + log_softmax ----
  matmul40_kernel<<<NN / 32, 256, 0, stream>>>(h, W10, sup40);
  spmm40_lsm_kernel<<<NN, 64, 0, stream>>>(sup40, rp, cs, cw, b10, out);
}

// Round 4
// 1101.489 us; speedup vs baseline: 1.7991x; 1.2861x over previous
//
#include <hip/hip_runtime.h>
#include <math.h>

#define NN 100000
#define NE 800000
#define NH 128
#define NC 40
#define NB_SCAN 98   // ceil(NN/1024)

typedef __attribute__((ext_vector_type(8))) short short8;
typedef __attribute__((ext_vector_type(4))) float floatx4;

__device__ __forceinline__ unsigned short f2b(float f) {
  union { float f; unsigned int u; } x; x.f = f;
  unsigned int r = x.u + 0x7fff + ((x.u >> 16) & 1);  // RTNE
  return (unsigned short)(r >> 16);
}
__device__ __forceinline__ float b2f(unsigned short h) {
  union { unsigned int u; float f; } x; x.u = ((unsigned int)h) << 16;
  return x.f;
}

// ---------------- CSR build ----------------
__global__ void hist_kernel(const int* __restrict__ dst, int* __restrict__ cnt, int E) {
  int i = blockIdx.x * 256 + threadIdx.x;
  if (i < E) atomicAdd(&cnt[dst[i]], 1);
}

__global__ __launch_bounds__(1024) void scan1_kernel(const int* __restrict__ cnt,
                                                     int* __restrict__ rp,
                                                     int* __restrict__ bsum, int n) {
  __shared__ int buf[1024];
  int t = threadIdx.x, i = blockIdx.x * 1024 + t;
  int v = (i < n) ? cnt[i] : 0;
  buf[t] = v;
  __syncthreads();
  for (int off = 1; off < 1024; off <<= 1) {
    int x = (t >= off) ? buf[t - off] : 0;
    __syncthreads();
    buf[t] += x;
    __syncthreads();
  }
  if (i < n) rp[i] = buf[t] - v;
  if (t == 1023) bsum[blockIdx.x] = buf[t];
}

__global__ __launch_bounds__(128) void scan2_kernel(const int* __restrict__ bsum,
                                                    int* __restrict__ boff, int nb) {
  __shared__ int buf[128];
  int t = threadIdx.x;
  int v = (t < nb) ? bsum[t] : 0;
  buf[t] = v;
  __syncthreads();
  for (int off = 1; off < 128; off <<= 1) {
    int x = (t >= off) ? buf[t - off] : 0;
    __syncthreads();
    buf[t] += x;
    __syncthreads();
  }
  if (t < nb) boff[t] = buf[t] - v;
  if (t == 127) boff[nb] = buf[t];  // grand total
}

__global__ void scan3_kernel(int* __restrict__ rp, const int* __restrict__ boff,
                             int n, int nb) {
  int i = blockIdx.x * 256 + threadIdx.x;
  if (i < n) rp[i] += boff[i >> 10];
  if (i == 0) rp[n] = boff[nb];
}

__global__ void copy_kernel(const int* __restrict__ a, int* __restrict__ b, int n) {
  int i = blockIdx.x * 256 + threadIdx.x;
  if (i < n) b[i] = a[i];
}

__global__ void scatter_kernel(const int* __restrict__ src, const int* __restrict__ dst,
                               const float* __restrict__ ew, int* __restrict__ off,
                               int* __restrict__ cs, float* __restrict__ cw, int E) {
  int i = blockIdx.x * 256 + threadIdx.x;
  if (i < E) {
    int p = atomicAdd(&off[dst[i]], 1);
    cs[p] = src[i];
    cw[p] = ew[i];
  }
}

// ---------------- prep: fp32 -> bf16 converts ----------------
__global__ void xconv_kernel(const float* __restrict__ in, unsigned short* __restrict__ out,
                             int n4) {
  int i = blockIdx.x * 256 + threadIdx.x;
  if (i < n4) {
    float4 v = ((const float4*)in)[i];
    out[4 * i + 0] = f2b(v.x);
    out[4 * i + 1] = f2b(v.y);
    out[4 * i + 2] = f2b(v.z);
    out[4 * i + 3] = f2b(v.w);
  }
}

// 9 dense-128 weights -> bf16, TRANSPOSED: WT[l][n][k] = W_l[k][n]
__global__ void wconv_kernel(const float* __restrict__ W1, const float* __restrict__ Wh,
                             unsigned short* __restrict__ WT) {
  int idx = blockIdx.x * 256 + threadIdx.x;  // 9*16384
  if (idx >= 9 * 16384) return;
  int l = idx >> 14, r = idx & 16383;        // r = k*128+n (coalesced read)
  int k = r >> 7, n = r & 127;
  const float* W = (l == 0) ? W1 : (Wh + (size_t)(l - 1) * 16384);
  WT[(size_t)l * 16384 + n * 128 + k] = f2b(W[r]);
}

// ---------------- MFMA matmul: [NN,128](bf16) @ WT[128,128](bf16) -> Sb bf16 ----------------
// block = 256 thr (4 waves), 128 rows/block; wave w owns 64x64 quadrant:
//   rows (w>>1)*64 .. +63, cols (w&1)*64 .. +63  (4 m-tiles x 4 n-tiles of 16x16)
// ds_read_b128 : MFMA = 8 : 16 per ks-step -> below the 0.4 LDS-bound threshold
#define LDH 136  // padded LDS row stride (shorts): 272 B -> 2-way bank alias only (free)
__global__ __launch_bounds__(256) void matmul_mfma_kernel(const unsigned short* __restrict__ Hb,
                                                          const unsigned short* __restrict__ WT,
                                                          unsigned short* __restrict__ Sb) {
  __shared__ unsigned short Ws[128 * LDH];  // W^T[n][k]
  __shared__ unsigned short Hs[128 * LDH];  // 128 H rows
  int tid = threadIdx.x;
  int row0 = blockIdx.x * 128;

  for (int c = tid; c < 2048; c += 256) {   // 128 rows x 16 chunks of 8 shorts
    int r = c >> 4, s = c & 15;
    *(short8*)(Ws + r * LDH + s * 8) = *(const short8*)(WT + r * 128 + s * 8);
  }
  for (int c = tid; c < 2048; c += 256) {
    int r = c >> 4, s = c & 15;
    int gr = row0 + r; if (gr >= NN) gr = NN - 1;
    *(short8*)(Hs + r * LDH + s * 8) = *(const short8*)(Hb + (size_t)gr * 128 + s * 8);
  }
  __syncthreads();

  int wave = tid >> 6;
  int lane = tid & 63;
  int m = lane & 15;
  int quad = lane >> 4;
  int wr0 = (wave >> 1) * 64;   // wave row offset in block tile
  int wc0 = (wave & 1) * 64;    // wave col offset

  floatx4 acc[4][4];
#pragma unroll
  for (int mt = 0; mt < 4; ++mt)
#pragma unroll
    for (int nt = 0; nt < 4; ++nt) acc[mt][nt] = (floatx4){0.f, 0.f, 0.f, 0.f};

#pragma unroll
  for (int ks = 0; ks < 4; ++ks) {
    short8 a[4], b[4];
#pragma unroll
    for (int mt = 0; mt < 4; ++mt)
      a[mt] = *(const short8*)(Hs + (wr0 + mt * 16 + m) * LDH + quad * 8 + ks * 32);
#pragma unroll
    for (int nt = 0; nt < 4; ++nt)
      b[nt] = *(const short8*)(Ws + (wc0 + nt * 16 + m) * LDH + quad * 8 + ks * 32);
#pragma unroll
    for (int mt = 0; mt < 4; ++mt)
#pragma unroll
      for (int nt = 0; nt < 4; ++nt)
        acc[mt][nt] = __builtin_amdgcn_mfma_f32_16x16x32_bf16(a[mt], b[nt], acc[mt][nt], 0, 0, 0);
  }
  // D: row = quad*4+reg (within 16-tile), col = m
#pragma unroll
  for (int mt = 0; mt < 4; ++mt) {
#pragma unroll
    for (int reg = 0; reg < 4; ++reg) {
      int gr = row0 + wr0 + mt * 16 + quad * 4 + reg;
      if (gr < NN) {
#pragma unroll
        for (int nt = 0; nt < 4; ++nt)
          Sb[(size_t)gr * 128 + wc0 + nt * 16 + m] = f2b(acc[mt][nt][reg]);
      }
    }
  }
}

// ---------------- spmm (bf16 gather, 4-way unrolled) + bias + relu (+ residual) ----------------
__global__ __launch_bounds__(128) void spmm128b_kernel(const unsigned short* __restrict__ Sb,
                                                       const int* __restrict__ rp,
                                                       const int* __restrict__ cs,
                                                       const float* __restrict__ cw,
                                                       const float* __restrict__ b,
                                                       const float* __restrict__ Hin,
                                                       float* __restrict__ Hout,
                                                       unsigned short* __restrict__ HbOut,
                                                       int residual) {
  int node = blockIdx.x;
  int tid = threadIdx.x;
  int e0 = rp[node], e1 = rp[node + 1];
  float a0 = 0.f, a1 = 0.f, a2 = 0.f, a3 = 0.f;
  int e = e0;
  for (; e + 4 <= e1; e += 4) {
    int s0 = cs[e], s1 = cs[e + 1], s2 = cs[e + 2], s3 = cs[e + 3];
    float w0 = cw[e], w1 = cw[e + 1], w2 = cw[e + 2], w3 = cw[e + 3];
    unsigned short v0 = Sb[(size_t)s0 * NH + tid];
    unsigned short v1 = Sb[(size_t)s1 * NH + tid];
    unsigned short v2 = Sb[(size_t)s2 * NH + tid];
    unsigned short v3 = Sb[(size_t)s3 * NH + tid];
    a0 = fmaf(w0, b2f(v0), a0);
    a1 = fmaf(w1, b2f(v1), a1);
    a2 = fmaf(w2, b2f(v2), a2);
    a3 = fmaf(w3, b2f(v3), a3);
  }
  for (; e < e1; ++e)
    a0 = fmaf(cw[e], b2f(Sb[(size_t)cs[e] * NH + tid]), a0);
  float acc = (a0 + a1) + (a2 + a3);
  float v = fmaxf(acc + b[tid], 0.f);
  if (residual) v += Hin[(size_t)node * NH + tid];
  Hout[(size_t)node * NH + tid] = v;
  HbOut[(size_t)node * NH + tid] = f2b(v);
}

// ---------------- dense matmul: [NN,128](f32) @ [128,40] ----------------
__global__ __launch_bounds__(256) void matmul40_kernel(const float* __restrict__ H,
                                                       const float* __restrict__ W,
                                                       float* __restrict__ S) {
  __shared__ float Wsf[128 * NC + 64];
  __shared__ float4 Hs4[32 * 32];
  int tid = threadIdx.x;
  size_t row0 = (size_t)blockIdx.x * 32;

  for (int i = tid; i < 128 * NC / 4; i += 256) ((float4*)Wsf)[i] = ((const float4*)W)[i];
  const float4* H4 = (const float4*)(H + row0 * NH);
  for (int i = tid; i < 1024; i += 256) Hs4[i] = H4[i];
  __syncthreads();

  int c = tid & 63;
  int rg = tid >> 6;
  float acc[8];
#pragma unroll
  for (int r = 0; r < 8; ++r) acc[r] = 0.f;

  for (int kk = 0; kk < 32; ++kk) {
    float4 hv[8];
#pragma unroll
    for (int r = 0; r < 8; ++r) hv[r] = Hs4[(rg + 4 * r) * 32 + kk];
#pragma unroll
    for (int j = 0; j < 4; ++j) {
      float wv = Wsf[(4 * kk + j) * NC + c];
#pragma unroll
      for (int r = 0; r < 8; ++r) {
        float s = (j == 0) ? hv[r].x : (j == 1) ? hv[r].y : (j == 2) ? hv[r].z : hv[r].w;
        acc[r] = fmaf(s, wv, acc[r]);
      }
    }
  }
  if (c < NC) {
#pragma unroll
    for (int r = 0; r < 8; ++r) S[(row0 + rg + 4 * r) * NC + c] = acc[r];
  }
}

// ---------------- final spmm (40-wide) + bias + relu + log_softmax ----------------
__global__ __launch_bounds__(64) void spmm40_lsm_kernel(const float* __restrict__ S,
                                                        const int* __restrict__ rp,
                                                        const int* __restrict__ cs,
                                                        const float* __restrict__ cw,
                                                        const float* __restrict__ b,
                                                        float* __restrict__ out) {
  int node = blockIdx.x;
  int tid = threadIdx.x;
  int e0 = rp[node], e1 = rp[node + 1];
  float acc = 0.f;
  if (tid < NC) {
    for (int e = e0; e < e1; ++e)
      acc = fmaf(cw[e], S[(size_t)cs[e] * NC + tid], acc);
    acc = fmaxf(acc + b[tid], 0.f);
  }
  float v = (tid < NC) ? acc : -INFINITY;
  float m = v;
#pragma unroll
  for (int off = 32; off; off >>= 1) m = fmaxf(m, __shfl_xor(m, off));
  float ex = (tid < NC) ? expf(v - m) : 0.f;
  float ssum = ex;
#pragma unroll
  for (int off = 32; off; off >>= 1) ssum += __shfl_xor(ssum, off);
  if (tid < NC) out[(size_t)node * NC + tid] = v - m - logf(ssum);
}

extern "C" void kernel_launch(void* const* d_in, const int* in_sizes, int n_in,
                              void* d_out, int out_size, void* d_ws, size_t ws_size,
                              hipStream_t stream) {
  const float* x   = (const float*)d_in[0];
  const int*   src = (const int*)d_in[1];
  const int*   dst = (const int*)d_in[2];
  const float* ew  = (const float*)d_in[3];
  const float* W1  = (const float*)d_in[4];
  const float* Wh  = (const float*)d_in[5];
  const float* W10 = (const float*)d_in[6];
  const float* b1  = (const float*)d_in[7];
  const float* bh  = (const float*)d_in[8];
  const float* b10 = (const float*)d_in[9];
  float* out = (float*)d_out;

  // workspace layout (256B-aligned chunks)
  char* p = (char*)d_ws;
  int*   rp    = (int*)p;            p += (((size_t)(NN + 1) * 4 + 255) / 256) * 256;
  int*   roff  = (int*)p;            p += (((size_t)NN * 4 + 255) / 256) * 256;
  int*   bsum  = (int*)p;            p += 256 * 4;
  int*   boff  = (int*)p;            p += 256 * 4;
  int*   cs    = (int*)p;            p += (size_t)NE * 4;
  float* cw    = (float*)p;          p += (size_t)NE * 4;
  float* h     = (float*)p;          p += (size_t)NN * NH * 4;
  unsigned short* hb   = (unsigned short*)p; p += (size_t)NN * NH * 2;  // also x-bf16
  unsigned short* supb = (unsigned short*)p; p += (size_t)NN * NH * 2;
  float* sup40 = (float*)p;          p += (size_t)NN * NC * 4;
  unsigned short* WT   = (unsigned short*)p; p += (size_t)9 * NH * NH * 2;

  // ---- build CSR ----
  hipMemsetAsync(roff, 0, (size_t)NN * 4, stream);
  hist_kernel<<<(NE + 255) / 256, 256, 0, stream>>>(dst, roff, NE);
  scan1_kernel<<<NB_SCAN, 1024, 0, stream>>>(roff, rp, bsum, NN);
  scan2_kernel<<<1, 128, 0, stream>>>(bsum, boff, NB_SCAN);
  scan3_kernel<<<(NN + 255) / 256, 256, 0, stream>>>(rp, boff, NN, NB_SCAN);
  copy_kernel<<<(NN + 255) / 256, 256, 0, stream>>>(rp, roff, NN);
  scatter_kernel<<<(NE + 255) / 256, 256, 0, stream>>>(src, dst, ew, roff, cs, cw, NE);

  // ---- prep converts ----
  xconv_kernel<<<(NN * NH / 4 + 255) / 256, 256, 0, stream>>>(x, hb, NN * NH / 4);
  wconv_kernel<<<(9 * 16384 + 255) / 256, 256, 0, stream>>>(W1, Wh, WT);

  // ---- layer 1 ----
  matmul_mfma_kernel<<<(NN + 127) / 128, 256, 0, stream>>>(hb, WT, supb);
  spmm128b_kernel<<<NN, 128, 0, stream>>>(supb, rp, cs, cw, b1, h, h, hb, 0);

  // ---- 8 hidden residual layers ----
  for (int i = 0; i < 8; ++i) {
    matmul_mfma_kernel<<<(NN + 127) / 128, 256, 0, stream>>>(hb, WT + (size_t)(i + 1) * NH * NH, supb);
    spmm128b_kernel<<<NN, 128, 0, stream>>>(supb, rp, cs, cw, bh + (size_t)i * NH, h, h, hb, 1);
  }

  // ---- final layer + log_softmax ----
  matmul40_kernel<<<NN / 32, 256, 0, stream>>>(h, W10, sup40);
  spmm40_lsm_kernel<<<NN, 64, 0, stream>>>(sup40, rp, cs, cw, b10, out);
}